// Round 17
// baseline (281.597 us; speedup 1.0000x reference)
//
#include <hip/hip_runtime.h>
#include <hip/hip_fp16.h>

#define NV    6890
#define NQ    32768
#define DF    64
#define NW    16      // waves per knn block
#define CHUNK 431     // ceil(NV/16)
#define SAMP  32      // sample vertices per wave (16*32 = 512 total)
#define CAPQ  20      // queue slots per lane (+1 trash slot)

typedef _Float16 v8h  __attribute__((ext_vector_type(8)));
typedef float    f32x4 __attribute__((ext_vector_type(4)));
typedef unsigned int       u32;
typedef unsigned long long u64;
typedef unsigned short     u16;

// ---- workspace layout (bytes) ----
static constexpr size_t VTX4_OFF  = 0;                               // float4[6912]
static constexpr size_t KIDX_OFF  = 110592;                          // int[NQ*8]
static constexpr size_t KW_OFF    = KIDX_OFF + (size_t)NQ * 8 * 4;   // float[NQ*8]
static constexpr size_t WFRAG_OFF = KW_OFF + (size_t)NQ * 8 * 4;     // f16[53248]

__device__ __forceinline__ u32 monof(float s) {
    u32 u = __float_as_uint(s);
    return (u & 0x80000000u) ? ~u : (u | 0x80000000u);
}

__device__ __forceinline__ float rlane(float x, int q) {
    return __uint_as_float((u32)__builtin_amdgcn_readlane((int)__float_as_uint(x), q));
}

// distance-only sorted top-8 insert (ascending), ~24 VALU.
#define DINSERT(sv) do {                                               \
    bool c0 = (sv) < dbest[0], c1 = (sv) < dbest[1],                   \
         c2 = (sv) < dbest[2], c3 = (sv) < dbest[3],                   \
         c4 = (sv) < dbest[4], c5 = (sv) < dbest[5],                   \
         c6 = (sv) < dbest[6], c7 = (sv) < dbest[7];                   \
    dbest[7] = c7 ? (c6 ? dbest[6] : (sv)) : dbest[7];                 \
    dbest[6] = c6 ? (c5 ? dbest[5] : (sv)) : dbest[6];                 \
    dbest[5] = c5 ? (c4 ? dbest[4] : (sv)) : dbest[5];                 \
    dbest[4] = c4 ? (c3 ? dbest[3] : (sv)) : dbest[4];                 \
    dbest[3] = c3 ? (c2 ? dbest[2] : (sv)) : dbest[3];                 \
    dbest[2] = c2 ? (c1 ? dbest[1] : (sv)) : dbest[2];                 \
    dbest[1] = c1 ? (c0 ? dbest[0] : (sv)) : dbest[1];                 \
    dbest[0] = c0 ? (sv) : dbest[0];                                   \
} while (0)

// u64 sorted top-8 insert (ascending). Compares precomputed; uses OLD values.
#define KINSERT(nk) do {                                  \
    bool c0 = (nk) < key[0], c1 = (nk) < key[1],          \
         c2 = (nk) < key[2], c3 = (nk) < key[3],          \
         c4 = (nk) < key[4], c5 = (nk) < key[5],          \
         c6 = (nk) < key[6], c7 = (nk) < key[7];          \
    key[7] = c7 ? (c6 ? key[6] : (nk)) : key[7];          \
    key[6] = c6 ? (c5 ? key[5] : (nk)) : key[6];          \
    key[5] = c5 ? (c4 ? key[4] : (nk)) : key[5];          \
    key[4] = c4 ? (c3 ? key[3] : (nk)) : key[4];          \
    key[3] = c3 ? (c2 ? key[2] : (nk)) : key[3];          \
    key[2] = c2 ? (c1 ? key[1] : (nk)) : key[2];          \
    key[1] = c1 ? (c0 ? key[0] : (nk)) : key[1];          \
    key[0] = c0 ? (nk) : key[0];                          \
} while (0)

// prep: pack vertices {x,y,z,0.5|v|^2} only (wfrag fused into knn grid).
__global__ void prep_kernel(const float* __restrict__ vtx, float4* __restrict__ vtx4) {
    int i = blockIdx.x * 256 + threadIdx.x;
    if (i < NV) {
        float x = vtx[i * 3 + 0], y = vtx[i * 3 + 1], z = vtx[i * 3 + 2];
        vtx4[i] = make_float4(x, y, z, 0.5f * (x * x + y * y + z * z));
    }
}

__device__ __forceinline__ float vdist(const float4 v, float nqx, float nqy, float nqz) {
    float s = fmaf(nqx, v.x, v.w);
    s = fmaf(nqy, v.y, s);
    return fmaf(nqz, v.z, s);
}

// Exact two-phase KNN, register-tiled transposed scan.
// Block = 64 queries (1/lane) x 16 waves; blocks >= 512 do the wfrag swizzle.
// Phase A: distance-only top-8 over 32-vertex sample slice -> LDS tree reduce
//   -> exact T = 8th smallest of 512-sample (s-space), Tbc broadcast.
// Scan (NEW): per pass, wave loads 64 vertices into REGISTERS (1 coalesced
//   dwordx4/lane; no wave-uniform scalar stream -> no K$/L2 latency stream).
//   Then iterates the 64 queries as the uniform axis: readlane broadcasts
//   (x,y,z,T) of query q; ballot-compacted append of surviving vertex ids
//   into qq[w][q][.]; lane q keeps the count (-> count ends in lane l for
//   query l, matching the drain). Exact same survivor set as R13.
// Overflow (P~1e-5): exec-masked exact rescan (wave-uniform s_loads, rare).
// Drain: batches of 4, exact u64 keys = (monotone(s)<<16)|idx (reproduces
//   top_k (distance,index) order). Merge: log2 tree over 16 lists.
__global__ __launch_bounds__(1024, 8) void knn_kernel(const float4* __restrict__ vtx4,
                                                      const float* __restrict__ qpts,
                                                      int* __restrict__ kidx,
                                                      float* __restrict__ kw,
                                                      const float* __restrict__ W0,
                                                      const float* __restrict__ W1,
                                                      const float* __restrict__ W2,
                                                      const float* __restrict__ W3,
                                                      _Float16* __restrict__ wfrag) {
    if (blockIdx.x >= NQ / 64) {
        // ---- fused weight-fragment swizzle: tile t=kt*NCT+ct, elem=
        // t*512+lane*8+jj, k=kt*32+(lane>>4)*8+jj, col=ct*16+(lane&15) ----
        int e = (blockIdx.x - NQ / 64) * 1024 + threadIdx.x;   // 0..53247
        const float* W; int base, NCT, C, KD;
        if      (e < 12288) { W = W0; base = 0;     NCT = 8; C = 128; KD = 67;  }
        else if (e < 28672) { W = W1; base = 12288; NCT = 8; C = 128; KD = 128; }
        else if (e < 45056) { W = W2; base = 28672; NCT = 8; C = 128; KD = 128; }
        else                { W = W3; base = 45056; NCT = 4; C = 64;  KD = 128; }
        int le = e - base;
        int t = le >> 9, r = le & 511;
        int lane = r >> 3, jj = r & 7;
        int kt = t / NCT, ct = t % NCT;
        int k = kt * 32 + (lane >> 4) * 8 + jj;
        int col = ct * 16 + (lane & 15);
        float v = (k < KD) ? W[k * C + col] : 0.0f;
        wfrag[e] = (_Float16)v;
        return;
    }

    __shared__ u64   kbuf[8][64][9];        // 36864 B; aliased f32[16][64][9] in phase A
    __shared__ u16   qq[NW][64][CAPQ + 1];  // 43008 B: [wave][query][slot]
    __shared__ float Tbc[64];
    float (*fbuf)[64][9] = (float (*)[64][9])kbuf;

    const int tid = threadIdx.x, w = tid >> 6, l = tid & 63;
    const int m = blockIdx.x * 64 + l;
    const float qx = qpts[m * 3 + 0], qy = qpts[m * 3 + 1], qz = qpts[m * 3 + 2];
    const float nqx = -qx, nqy = -qy, nqz = -qz;

    // ---- phase A: per-wave 32-vertex sample, distance-only top-8 ----
    float dbest[8];
#pragma unroll
    for (int i = 0; i < 8; ++i) dbest[i] = 3.0e38f;
    {
        const int s0 = w * SAMP;
#pragma unroll 4
        for (int j = s0; j < s0 + SAMP; ++j) {
            float s = vdist(vtx4[j], nqx, nqy, nqz);   // wave-uniform -> s_load
            DINSERT(s);
        }
    }
#pragma unroll
    for (int i = 0; i < 8; ++i) fbuf[w][l][i] = dbest[i];
    __syncthreads();

    // ---- T tree-reduce: read [st,2st) slots, merge, write [0,st) ----
#pragma unroll 1
    for (int st = 8; st >= 1; st >>= 1) {
        if (w < st) {
#pragma unroll
            for (int e = 0; e < 8; ++e) {
                float s = fbuf[w + st][l][e];
                if (s < dbest[7]) { DINSERT(s); }
            }
            if (st > 1) {
#pragma unroll
                for (int i = 0; i < 8; ++i) fbuf[w][l][i] = dbest[i];
            }
        }
        __syncthreads();
    }
    if (w == 0) Tbc[l] = dbest[7];
    __syncthreads();
    const float T = Tbc[l];

    // ---- scan: register vertex tile, query-uniform iteration ----
    u64 key[8];
#pragma unroll
    for (int i = 0; i < 8; ++i) key[i] = ~0ull;
    u32 mycnt = 0;
    const int j0 = w * CHUNK;
    const int j1 = (j0 + CHUNK < NV) ? j0 + CHUNK : NV;
#pragma unroll 1
    for (int jb = j0; jb < j1; jb += 64) {
        const int  jl  = jb + l;
        const bool vld = jl < j1;
        float4 v = vtx4[jl < NV ? jl : NV - 1];   // coalesced per-lane dwordx4
#pragma unroll 2
        for (int q = 0; q < 64; ++q) {
            float sx = rlane(qx, q), sy = rlane(qy, q), sz = rlane(qz, q);
            float sT = rlane(T, q);
            float s = fmaf(-sx, v.x, v.w);
            s = fmaf(-sy, v.y, s);
            s = fmaf(-sz, v.z, s);
            bool c = vld && (s <= sT);
            u64 mask = __ballot(c);
            if (mask) {
                u32 base = (u32)__builtin_amdgcn_readlane((int)mycnt, q);
                u32 rank = __builtin_amdgcn_mbcnt_hi((u32)(mask >> 32),
                           __builtin_amdgcn_mbcnt_lo((u32)mask, 0));
                if (c) {
                    u32 pos = base + rank;
                    pos = pos < CAPQ ? pos : CAPQ;   // trash slot on overflow
                    qq[w][q][pos] = (u16)jl;
                }
                u32 tot = (u32)__popcll(mask);
                mycnt = (l == q) ? (mycnt + tot) : mycnt;
            }
        }
    }
    u32 cnt = mycnt;    // lane l now holds the survivor count for query l

    // ---- overflow fallback (P ~ 1e-5 per lane): exact exec-masked rescan ----
    if (__any(cnt > CAPQ)) {
        bool ovf = cnt > CAPQ;
        if (ovf) cnt = 0;
#pragma unroll 1
        for (int j = j0; j < j1; ++j) {
            if (ovf) {
                float s = vdist(vtx4[j], nqx, nqy, nqz);
                if (s <= T) {
                    u64 nk = ((u64)monof(s) << 16) | (u64)j;
                    if (nk < key[7]) { KINSERT(nk); }
                }
            }
        }
    }

    // ---- drain queue in batches of 4 (exact keys) ----
#pragma unroll 1
    for (int b = 0; b < CAPQ; b += 4) {
        if (!__any(cnt > (u32)b)) break;
        u32 jj[4]; float4 vv[4];
#pragma unroll
        for (int t = 0; t < 4; ++t) {
            u32 qi = ((u32)(b + t) < cnt) ? (u32)qq[w][l][b + t] : 0u;
            jj[t] = qi; vv[t] = vtx4[qi];
        }
#pragma unroll
        for (int t = 0; t < 4; ++t) {
            float s = vdist(vv[t], nqx, nqy, nqz);
            u64 nk = ((u64)monof(s) << 16) | (u64)jj[t];
            nk = ((u32)(b + t) < cnt) ? nk : ~0ull;
            if (nk < key[7]) { KINSERT(nk); }
        }
    }

    // ---- tree merge of 16 key lists: publish [st,2st) -> merge on [0,st) ----
#pragma unroll 1
    for (int st = 8; st >= 1; st >>= 1) {
        if (w >= st && w < 2 * st) {
#pragma unroll
            for (int i = 0; i < 8; ++i) kbuf[w - st][l][i] = key[i];
        }
        __syncthreads();
        if (w < st) {
#pragma unroll
            for (int e = 0; e < 8; ++e) {
                u64 nk = kbuf[w][l][e];
                if (nk < key[7]) { KINSERT(nk); }
            }
        }
        __syncthreads();
    }

    // ---- wave 0: weights + output ----
    if (w == 0) {
        float q2 = fmaf(qx, qx, fmaf(qy, qy, qz * qz));
        float inv[8], ssum = 0.0f;
        int idx8[8];
#pragma unroll
        for (int i = 0; i < 8; ++i) {
            u32 us = (u32)(key[i] >> 16);
            u32 uo = (us & 0x80000000u) ? (us & 0x7FFFFFFFu) : ~us;
            float s = __uint_as_float(uo);
            float dd = fmaf(2.0f, s, q2);
            float d = sqrtf(fmaxf(dd, 0.0f)) + 1e-9f;
            inv[i] = 1.0f / d; ssum += inv[i];
            idx8[i] = (int)(key[i] & 0xFFFFull);
        }
        float rs = 1.0f / ssum;
#pragma unroll
        for (int i = 0; i < 8; ++i) {
            kidx[m * 8 + i] = idx8[i];
            kw[m * 8 + i]   = inv[i] * rs;
        }
    }
}

// One MLP layer on this wave's 32 rows, in-place in buf. A-frag: row=l&15(+16*rt),
// k=(l>>4)*8+j; B-frag preswizzled with the SAME (lane,j)->k map (k-perm cancels).
template <int KSTEPS, int NCT, bool RELU>
__device__ __forceinline__ void mlp_layer(_Float16 (*buf)[136],
                                          const _Float16* __restrict__ frag,
                                          const float* __restrict__ bias,
                                          int w, int l) {
    const int cl = l & 15, gl = l >> 4;
    f32x4 acc[2][NCT];
#pragma unroll
    for (int ct = 0; ct < NCT; ++ct) {
        float bv = bias[ct * 16 + cl];
#pragma unroll
        for (int rt = 0; rt < 2; ++rt) acc[rt][ct] = (f32x4){bv, bv, bv, bv};
    }
    const _Float16* fb = frag + (size_t)l * 8;
#pragma unroll 1
    for (int ks = 0; ks < KSTEPS; ++ks) {
        v8h a0 = *(const v8h*)&buf[w * 32 + cl][ks * 32 + gl * 8];
        v8h a1 = *(const v8h*)&buf[w * 32 + 16 + cl][ks * 32 + gl * 8];
#pragma unroll
        for (int ct = 0; ct < NCT; ++ct) {
            v8h bf = *(const v8h*)(fb + (size_t)(ks * NCT + ct) * 512);
            acc[0][ct] = __builtin_amdgcn_mfma_f32_16x16x32_f16(a0, bf, acc[0][ct], 0, 0, 0);
            acc[1][ct] = __builtin_amdgcn_mfma_f32_16x16x32_f16(a1, bf, acc[1][ct], 0, 0, 0);
        }
    }
    // C/D layout (m89-verified): row=(l>>4)*4+j, col=l&15
#pragma unroll
    for (int rt = 0; rt < 2; ++rt)
#pragma unroll
        for (int ct = 0; ct < NCT; ++ct)
#pragma unroll
            for (int j = 0; j < 4; ++j) {
                float v = acc[rt][ct][j];
                if (RELU) v = fmaxf(v, 0.0f);
                buf[w * 32 + rt * 16 + gl * 4 + j][ct * 16 + cl] = (_Float16)v;
            }
}

// Block = 128 rows (16 queries x 8 NB), 4 waves, each wave owns 32 rows.
__global__ __launch_bounds__(256, 3) void mlp_kernel(
    const float* __restrict__ vf, const float4* __restrict__ vtx4,
    const float* __restrict__ qpts,
    const int* __restrict__ kidx, const float* __restrict__ kw,
    const _Float16* __restrict__ wfrag,
    const float* __restrict__ b0, const float* __restrict__ b1,
    const float* __restrict__ b2, const float* __restrict__ b3,
    float* __restrict__ out) {
    __shared__ _Float16 buf[128][136];
    const int tid = threadIdx.x, w = tid >> 6, l = tid & 63;
    {
        int h = l & 1;
        int lrow = w * 32 + (l >> 1);
        int grow = blockIdx.x * 128 + lrow;
        int q = grow >> 3;
        int idx = kidx[grow];
        const float4* src = (const float4*)(vf + (size_t)idx * DF) + h * 8;
#pragma unroll
        for (int t = 0; t < 4; ++t) {
            float4 a = src[2 * t], b = src[2 * t + 1];
            v8h pk = {(_Float16)a.x, (_Float16)a.y, (_Float16)a.z, (_Float16)a.w,
                      (_Float16)b.x, (_Float16)b.y, (_Float16)b.z, (_Float16)b.w};
            *(v8h*)&buf[lrow][h * 32 + t * 8] = pk;
        }
        v8h zz = {0, 0, 0, 0, 0, 0, 0, 0};
        if (h == 0) {
            float4 v = vtx4[idx];
            float qx = qpts[q * 3 + 0], qy = qpts[q * 3 + 1], qz = qpts[q * 3 + 2];
            v8h d = {(_Float16)(qx - v.x), (_Float16)(qy - v.y), (_Float16)(qz - v.z),
                     0, 0, 0, 0, 0};
            *(v8h*)&buf[lrow][64] = d;
            *(v8h*)&buf[lrow][88] = zz;
        } else {
            *(v8h*)&buf[lrow][72] = zz;
            *(v8h*)&buf[lrow][80] = zz;
        }
    }

    mlp_layer<3, 8, true>(buf, wfrag + 0,     b0, w, l);
    mlp_layer<4, 8, true>(buf, wfrag + 12288, b1, w, l);
    mlp_layer<4, 8, true>(buf, wfrag + 28672, b2, w, l);

    {
        const int cl = l & 15, gl = l >> 4;
        f32x4 acc[2][4];
#pragma unroll
        for (int ct = 0; ct < 4; ++ct) {
            float bv = b3[ct * 16 + cl];
#pragma unroll
            for (int rt = 0; rt < 2; ++rt) acc[rt][ct] = (f32x4){bv, bv, bv, bv};
        }
        const _Float16* fb = wfrag + 45056 + (size_t)l * 8;
#pragma unroll 1
        for (int ks = 0; ks < 4; ++ks) {
            v8h a0 = *(const v8h*)&buf[w * 32 + cl][ks * 32 + gl * 8];
            v8h a1 = *(const v8h*)&buf[w * 32 + 16 + cl][ks * 32 + gl * 8];
#pragma unroll
            for (int ct = 0; ct < 4; ++ct) {
                v8h bf = *(const v8h*)(fb + (size_t)(ks * 4 + ct) * 512);
                acc[0][ct] = __builtin_amdgcn_mfma_f32_16x16x32_f16(a0, bf, acc[0][ct], 0, 0, 0);
                acc[1][ct] = __builtin_amdgcn_mfma_f32_16x16x32_f16(a1, bf, acc[1][ct], 0, 0, 0);
            }
        }
        int GRbase = blockIdx.x * 128 + w * 32;
#pragma unroll
        for (int rt = 0; rt < 2; ++rt) {
            int r4 = GRbase + rt * 16 + gl * 4;
            float4 kv = *(const float4*)&kw[r4];
#pragma unroll
            for (int ct = 0; ct < 4; ++ct) {
                float v = acc[rt][ct][0] * kv.x + acc[rt][ct][1] * kv.y +
                          acc[rt][ct][2] * kv.z + acc[rt][ct][3] * kv.w;
                v += __shfl_xor(v, 16);
                if ((gl & 1) == 0) {
                    int q = (GRbase + rt * 16 + ((gl == 2) ? 8 : 0)) >> 3;
                    out[(size_t)q * 64 + ct * 16 + cl] = v;
                }
            }
        }
    }
}

extern "C" void kernel_launch(void* const* d_in, const int* in_sizes, int n_in,
                              void* d_out, int out_size, void* d_ws, size_t ws_size,
                              hipStream_t stream) {
    const float* vtx = (const float*)d_in[0];
    const float* vf  = (const float*)d_in[1];
    const float* qp  = (const float*)d_in[2];
    const float* W0  = (const float*)d_in[3];
    const float* b0  = (const float*)d_in[4];
    const float* W1  = (const float*)d_in[5];
    const float* b1  = (const float*)d_in[6];
    const float* W2  = (const float*)d_in[7];
    const float* b2  = (const float*)d_in[8];
    const float* W3  = (const float*)d_in[9];
    const float* b3  = (const float*)d_in[10];
    float*       out = (float*)d_out;

    char*      ws    = (char*)d_ws;
    float4*    vtx4  = (float4*)(ws + VTX4_OFF);
    int*       kidx  = (int*)(ws + KIDX_OFF);
    float*     kw    = (float*)(ws + KW_OFF);
    _Float16*  wfrag = (_Float16*)(ws + WFRAG_OFF);

    hipLaunchKernelGGL(prep_kernel, dim3(27), dim3(256), 0, stream, vtx, vtx4);
    hipLaunchKernelGGL(knn_kernel, dim3(NQ / 64 + 52), dim3(1024), 0, stream,
                       vtx4, qp, kidx, kw, W0, W1, W2, W3, wfrag);
    hipLaunchKernelGGL(mlp_kernel, dim3(NQ * 8 / 128), dim3(256), 0, stream,
                       vf, vtx4, qp, kidx, kw, wfrag, b0, b1, b2, b3, out);
}

// Round 18
// 239.682 us; speedup vs baseline: 1.1749x; 1.1749x over previous
//
#include <hip/hip_runtime.h>
#include <hip/hip_fp16.h>

#define NV    6890
#define NQ    32768
#define DF    64
#define NW    16      // waves per knn block
#define CHUNK 431     // ceil(NV/16)
#define SAMP  32      // sample vertices per wave (16*32 = 512 total)
#define CAPQ  20      // queue slots per lane (+1 trash slot)

typedef _Float16 v8h  __attribute__((ext_vector_type(8)));
typedef float    f32x4 __attribute__((ext_vector_type(4)));
typedef unsigned int       u32;
typedef unsigned long long u64;
typedef unsigned short     u16;

// ---- workspace layout (bytes) ----
static constexpr size_t VTX4_OFF  = 0;                               // float4[6912]
static constexpr size_t KIDX_OFF  = 110592;                          // int[NQ*8]
static constexpr size_t KW_OFF    = KIDX_OFF + (size_t)NQ * 8 * 4;   // float[NQ*8]
static constexpr size_t WFRAG_OFF = KW_OFF + (size_t)NQ * 8 * 4;     // f16[53248]

__device__ __forceinline__ u32 monof(float s) {
    u32 u = __float_as_uint(s);
    return (u & 0x80000000u) ? ~u : (u | 0x80000000u);
}

// distance-only sorted top-8 insert (ascending), ~24 VALU.
#define DINSERT(sv) do {                                               \
    bool c0 = (sv) < dbest[0], c1 = (sv) < dbest[1],                   \
         c2 = (sv) < dbest[2], c3 = (sv) < dbest[3],                   \
         c4 = (sv) < dbest[4], c5 = (sv) < dbest[5],                   \
         c6 = (sv) < dbest[6], c7 = (sv) < dbest[7];                   \
    dbest[7] = c7 ? (c6 ? dbest[6] : (sv)) : dbest[7];                 \
    dbest[6] = c6 ? (c5 ? dbest[5] : (sv)) : dbest[6];                 \
    dbest[5] = c5 ? (c4 ? dbest[4] : (sv)) : dbest[5];                 \
    dbest[4] = c4 ? (c3 ? dbest[3] : (sv)) : dbest[4];                 \
    dbest[3] = c3 ? (c2 ? dbest[2] : (sv)) : dbest[3];                 \
    dbest[2] = c2 ? (c1 ? dbest[1] : (sv)) : dbest[2];                 \
    dbest[1] = c1 ? (c0 ? dbest[0] : (sv)) : dbest[1];                 \
    dbest[0] = c0 ? (sv) : dbest[0];                                   \
} while (0)

// u64 sorted top-8 insert (ascending). Compares precomputed; uses OLD values.
#define KINSERT(nk) do {                                  \
    bool c0 = (nk) < key[0], c1 = (nk) < key[1],          \
         c2 = (nk) < key[2], c3 = (nk) < key[3],          \
         c4 = (nk) < key[4], c5 = (nk) < key[5],          \
         c6 = (nk) < key[6], c7 = (nk) < key[7];          \
    key[7] = c7 ? (c6 ? key[6] : (nk)) : key[7];          \
    key[6] = c6 ? (c5 ? key[5] : (nk)) : key[6];          \
    key[5] = c5 ? (c4 ? key[4] : (nk)) : key[5];          \
    key[4] = c4 ? (c3 ? key[3] : (nk)) : key[4];          \
    key[3] = c3 ? (c2 ? key[2] : (nk)) : key[3];          \
    key[2] = c2 ? (c1 ? key[1] : (nk)) : key[2];          \
    key[1] = c1 ? (c0 ? key[0] : (nk)) : key[1];          \
    key[0] = c0 ? (nk) : key[0];                          \
} while (0)

// Single-branch queue append: trash slot CAPQ absorbs overflow; writes stay
// exec-masked-sparse (low bank conflicts, unlike unconditional R14/R16).
#define TRYS(sv, jv) do {                                 \
    if ((sv) <= T) {                                      \
        qq[w][l][cnt < CAPQ ? cnt : CAPQ] = (u16)(jv);    \
        ++cnt;                                            \
    }                                                     \
} while (0)

// prep: pack vertices {x,y,z,0.5|v|^2} only (wfrag fused into knn grid).
__global__ void prep_kernel(const float* __restrict__ vtx, float4* __restrict__ vtx4) {
    int i = blockIdx.x * 256 + threadIdx.x;
    if (i < NV) {
        float x = vtx[i * 3 + 0], y = vtx[i * 3 + 1], z = vtx[i * 3 + 2];
        vtx4[i] = make_float4(x, y, z, 0.5f * (x * x + y * y + z * z));
    }
}

__device__ __forceinline__ float vdist(const float4 v, float nqx, float nqy, float nqz) {
    float s = fmaf(nqx, v.x, v.w);
    s = fmaf(nqy, v.y, s);
    return fmaf(nqz, v.z, s);
}

// Exact two-phase KNN (R13 structure + single-branch append).
// Block = 64 queries (1/lane) x 16 waves; blocks >= 512 do the wfrag swizzle.
// Phase A: distance-only top-8 over 32-vertex sample slice -> LDS tree reduce
//   -> exact T = 8th smallest of 512-sample.
// Scan: chunk of 431, unroll-8 wave-uniform s_load float4s, single-branch
//   trash-slot append. cnt > CAPQ (P~1e-5) -> exec-masked exact rescan.
// Drain: batches of 4, exact u64 keys = (monotone(s)<<16)|idx (reproduces
//   top_k (distance,index) order). Merge: log2 tree over 16 lists.
__global__ __launch_bounds__(1024, 8) void knn_kernel(const float4* __restrict__ vtx4,
                                                      const float* __restrict__ qpts,
                                                      int* __restrict__ kidx,
                                                      float* __restrict__ kw,
                                                      const float* __restrict__ W0,
                                                      const float* __restrict__ W1,
                                                      const float* __restrict__ W2,
                                                      const float* __restrict__ W3,
                                                      _Float16* __restrict__ wfrag) {
    if (blockIdx.x >= NQ / 64) {
        // ---- fused weight-fragment swizzle: tile t=kt*NCT+ct, elem=
        // t*512+lane*8+jj, k=kt*32+(lane>>4)*8+jj, col=ct*16+(lane&15) ----
        int e = (blockIdx.x - NQ / 64) * 1024 + threadIdx.x;   // 0..53247
        const float* W; int base, NCT, C, KD;
        if      (e < 12288) { W = W0; base = 0;     NCT = 8; C = 128; KD = 67;  }
        else if (e < 28672) { W = W1; base = 12288; NCT = 8; C = 128; KD = 128; }
        else if (e < 45056) { W = W2; base = 28672; NCT = 8; C = 128; KD = 128; }
        else                { W = W3; base = 45056; NCT = 4; C = 64;  KD = 128; }
        int le = e - base;
        int t = le >> 9, r = le & 511;
        int lane = r >> 3, jj = r & 7;
        int kt = t / NCT, ct = t % NCT;
        int k = kt * 32 + (lane >> 4) * 8 + jj;
        int col = ct * 16 + (lane & 15);
        float v = (k < KD) ? W[k * C + col] : 0.0f;
        wfrag[e] = (_Float16)v;
        return;
    }

    __shared__ u64   kbuf[8][64][9];        // 36864 B; aliased f32[16][64][9] in phase A
    __shared__ u16   qq[NW][64][CAPQ + 1];  // 43008 B (slot CAPQ = trash bin)
    __shared__ float Tbc[64];
    float (*fbuf)[64][9] = (float (*)[64][9])kbuf;

    const int tid = threadIdx.x, w = tid >> 6, l = tid & 63;
    const int m = blockIdx.x * 64 + l;
    const float qx = qpts[m * 3 + 0], qy = qpts[m * 3 + 1], qz = qpts[m * 3 + 2];
    const float nqx = -qx, nqy = -qy, nqz = -qz;

    // ---- phase A: per-wave 32-vertex sample, distance-only top-8 ----
    float dbest[8];
#pragma unroll
    for (int i = 0; i < 8; ++i) dbest[i] = 3.0e38f;
    {
        const int s0 = w * SAMP;
#pragma unroll 4
        for (int j = s0; j < s0 + SAMP; ++j) {
            float s = vdist(vtx4[j], nqx, nqy, nqz);   // wave-uniform -> s_load
            DINSERT(s);
        }
    }
#pragma unroll
    for (int i = 0; i < 8; ++i) fbuf[w][l][i] = dbest[i];
    __syncthreads();

    // ---- T tree-reduce: read [st,2st) slots, merge, write [0,st) ----
#pragma unroll 1
    for (int st = 8; st >= 1; st >>= 1) {
        if (w < st) {
#pragma unroll
            for (int e = 0; e < 8; ++e) {
                float s = fbuf[w + st][l][e];
                if (s < dbest[7]) { DINSERT(s); }
            }
            if (st > 1) {
#pragma unroll
                for (int i = 0; i < 8; ++i) fbuf[w][l][i] = dbest[i];
            }
        }
        __syncthreads();
    }
    if (w == 0) Tbc[l] = dbest[7];
    __syncthreads();
    const float T = Tbc[l];

    // ---- scan: full chunk, unroll-8, single-branch trash-slot append ----
    u64 key[8];
#pragma unroll
    for (int i = 0; i < 8; ++i) key[i] = ~0ull;
    u32 cnt = 0;
    const int j0 = w * CHUNK;
    const int j1 = (j0 + CHUNK < NV) ? j0 + CHUNK : NV;
    {
        int j = j0;
#pragma unroll 1
        for (; j + 8 <= j1; j += 8) {
            float4 va = vtx4[j + 0], vb = vtx4[j + 1], vc = vtx4[j + 2], vd = vtx4[j + 3];
            float4 ve = vtx4[j + 4], vf = vtx4[j + 5], vg = vtx4[j + 6], vh = vtx4[j + 7];
            float s0 = vdist(va, nqx, nqy, nqz);
            float s1 = vdist(vb, nqx, nqy, nqz);
            float s2 = vdist(vc, nqx, nqy, nqz);
            float s3 = vdist(vd, nqx, nqy, nqz);
            float s4 = vdist(ve, nqx, nqy, nqz);
            float s5 = vdist(vf, nqx, nqy, nqz);
            float s6 = vdist(vg, nqx, nqy, nqz);
            float s7 = vdist(vh, nqx, nqy, nqz);
            TRYS(s0, j + 0); TRYS(s1, j + 1); TRYS(s2, j + 2); TRYS(s3, j + 3);
            TRYS(s4, j + 4); TRYS(s5, j + 5); TRYS(s6, j + 6); TRYS(s7, j + 7);
        }
        for (; j < j1; ++j) {
            float s = vdist(vtx4[j], nqx, nqy, nqz);
            TRYS(s, j);
        }
    }

    // ---- overflow fallback (P ~ 1e-5 per lane): exact exec-masked rescan ----
    if (__any(cnt > CAPQ)) {
        bool ovf = cnt > CAPQ;
        if (ovf) cnt = 0;
#pragma unroll 1
        for (int j = j0; j < j1; ++j) {
            if (ovf) {
                float s = vdist(vtx4[j], nqx, nqy, nqz);
                if (s <= T) {
                    u64 nk = ((u64)monof(s) << 16) | (u64)j;
                    if (nk < key[7]) { KINSERT(nk); }
                }
            }
        }
    }

    // ---- drain queue in batches of 4 (exact keys) ----
#pragma unroll 1
    for (int b = 0; b < CAPQ; b += 4) {
        if (!__any(cnt > (u32)b)) break;
        u32 jj[4]; float4 vv[4];
#pragma unroll
        for (int t = 0; t < 4; ++t) {
            u32 qi = ((u32)(b + t) < cnt) ? (u32)qq[w][l][b + t] : 0u;
            jj[t] = qi; vv[t] = vtx4[qi];
        }
#pragma unroll
        for (int t = 0; t < 4; ++t) {
            float s = vdist(vv[t], nqx, nqy, nqz);
            u64 nk = ((u64)monof(s) << 16) | (u64)jj[t];
            nk = ((u32)(b + t) < cnt) ? nk : ~0ull;
            if (nk < key[7]) { KINSERT(nk); }
        }
    }

    // ---- tree merge of 16 key lists: publish [st,2st) -> merge on [0,st) ----
#pragma unroll 1
    for (int st = 8; st >= 1; st >>= 1) {
        if (w >= st && w < 2 * st) {
#pragma unroll
            for (int i = 0; i < 8; ++i) kbuf[w - st][l][i] = key[i];
        }
        __syncthreads();
        if (w < st) {
#pragma unroll
            for (int e = 0; e < 8; ++e) {
                u64 nk = kbuf[w][l][e];
                if (nk < key[7]) { KINSERT(nk); }
            }
        }
        __syncthreads();
    }

    // ---- wave 0: weights + output ----
    if (w == 0) {
        float q2 = fmaf(qx, qx, fmaf(qy, qy, qz * qz));
        float inv[8], ssum = 0.0f;
        int idx8[8];
#pragma unroll
        for (int i = 0; i < 8; ++i) {
            u32 us = (u32)(key[i] >> 16);
            u32 uo = (us & 0x80000000u) ? (us & 0x7FFFFFFFu) : ~us;
            float s = __uint_as_float(uo);
            float dd = fmaf(2.0f, s, q2);
            float d = sqrtf(fmaxf(dd, 0.0f)) + 1e-9f;
            inv[i] = 1.0f / d; ssum += inv[i];
            idx8[i] = (int)(key[i] & 0xFFFFull);
        }
        float rs = 1.0f / ssum;
#pragma unroll
        for (int i = 0; i < 8; ++i) {
            kidx[m * 8 + i] = idx8[i];
            kw[m * 8 + i]   = inv[i] * rs;
        }
    }
}

// One MLP layer on this wave's 32 rows, in-place in buf. A-frag: row=l&15(+16*rt),
// k=(l>>4)*8+j; B-frag preswizzled with the SAME (lane,j)->k map (k-perm cancels).
template <int KSTEPS, int NCT, bool RELU>
__device__ __forceinline__ void mlp_layer(_Float16 (*buf)[136],
                                          const _Float16* __restrict__ frag,
                                          const float* __restrict__ bias,
                                          int w, int l) {
    const int cl = l & 15, gl = l >> 4;
    f32x4 acc[2][NCT];
#pragma unroll
    for (int ct = 0; ct < NCT; ++ct) {
        float bv = bias[ct * 16 + cl];
#pragma unroll
        for (int rt = 0; rt < 2; ++rt) acc[rt][ct] = (f32x4){bv, bv, bv, bv};
    }
    const _Float16* fb = frag + (size_t)l * 8;
#pragma unroll 1
    for (int ks = 0; ks < KSTEPS; ++ks) {
        v8h a0 = *(const v8h*)&buf[w * 32 + cl][ks * 32 + gl * 8];
        v8h a1 = *(const v8h*)&buf[w * 32 + 16 + cl][ks * 32 + gl * 8];
#pragma unroll
        for (int ct = 0; ct < NCT; ++ct) {
            v8h bf = *(const v8h*)(fb + (size_t)(ks * NCT + ct) * 512);
            acc[0][ct] = __builtin_amdgcn_mfma_f32_16x16x32_f16(a0, bf, acc[0][ct], 0, 0, 0);
            acc[1][ct] = __builtin_amdgcn_mfma_f32_16x16x32_f16(a1, bf, acc[1][ct], 0, 0, 0);
        }
    }
    // C/D layout (m89-verified): row=(l>>4)*4+j, col=l&15
#pragma unroll
    for (int rt = 0; rt < 2; ++rt)
#pragma unroll
        for (int ct = 0; ct < NCT; ++ct)
#pragma unroll
            for (int j = 0; j < 4; ++j) {
                float v = acc[rt][ct][j];
                if (RELU) v = fmaxf(v, 0.0f);
                buf[w * 32 + rt * 16 + gl * 4 + j][ct * 16 + cl] = (_Float16)v;
            }
}

// Block = 128 rows (16 queries x 8 NB), 4 waves, each wave owns 32 rows.
__global__ __launch_bounds__(256, 3) void mlp_kernel(
    const float* __restrict__ vf, const float4* __restrict__ vtx4,
    const float* __restrict__ qpts,
    const int* __restrict__ kidx, const float* __restrict__ kw,
    const _Float16* __restrict__ wfrag,
    const float* __restrict__ b0, const float* __restrict__ b1,
    const float* __restrict__ b2, const float* __restrict__ b3,
    float* __restrict__ out) {
    __shared__ _Float16 buf[128][136];
    const int tid = threadIdx.x, w = tid >> 6, l = tid & 63;
    {
        int h = l & 1;
        int lrow = w * 32 + (l >> 1);
        int grow = blockIdx.x * 128 + lrow;
        int q = grow >> 3;
        int idx = kidx[grow];
        const float4* src = (const float4*)(vf + (size_t)idx * DF) + h * 8;
#pragma unroll
        for (int t = 0; t < 4; ++t) {
            float4 a = src[2 * t], b = src[2 * t + 1];
            v8h pk = {(_Float16)a.x, (_Float16)a.y, (_Float16)a.z, (_Float16)a.w,
                      (_Float16)b.x, (_Float16)b.y, (_Float16)b.z, (_Float16)b.w};
            *(v8h*)&buf[lrow][h * 32 + t * 8] = pk;
        }
        v8h zz = {0, 0, 0, 0, 0, 0, 0, 0};
        if (h == 0) {
            float4 v = vtx4[idx];
            float qx = qpts[q * 3 + 0], qy = qpts[q * 3 + 1], qz = qpts[q * 3 + 2];
            v8h d = {(_Float16)(qx - v.x), (_Float16)(qy - v.y), (_Float16)(qz - v.z),
                     0, 0, 0, 0, 0};
            *(v8h*)&buf[lrow][64] = d;
            *(v8h*)&buf[lrow][88] = zz;
        } else {
            *(v8h*)&buf[lrow][72] = zz;
            *(v8h*)&buf[lrow][80] = zz;
        }
    }

    mlp_layer<3, 8, true>(buf, wfrag + 0,     b0, w, l);
    mlp_layer<4, 8, true>(buf, wfrag + 12288, b1, w, l);
    mlp_layer<4, 8, true>(buf, wfrag + 28672, b2, w, l);

    {
        const int cl = l & 15, gl = l >> 4;
        f32x4 acc[2][4];
#pragma unroll
        for (int ct = 0; ct < 4; ++ct) {
            float bv = b3[ct * 16 + cl];
#pragma unroll
            for (int rt = 0; rt < 2; ++rt) acc[rt][ct] = (f32x4){bv, bv, bv, bv};
        }
        const _Float16* fb = wfrag + 45056 + (size_t)l * 8;
#pragma unroll 1
        for (int ks = 0; ks < 4; ++ks) {
            v8h a0 = *(const v8h*)&buf[w * 32 + cl][ks * 32 + gl * 8];
            v8h a1 = *(const v8h*)&buf[w * 32 + 16 + cl][ks * 32 + gl * 8];
#pragma unroll
            for (int ct = 0; ct < 4; ++ct) {
                v8h bf = *(const v8h*)(fb + (size_t)(ks * 4 + ct) * 512);
                acc[0][ct] = __builtin_amdgcn_mfma_f32_16x16x32_f16(a0, bf, acc[0][ct], 0, 0, 0);
                acc[1][ct] = __builtin_amdgcn_mfma_f32_16x16x32_f16(a1, bf, acc[1][ct], 0, 0, 0);
            }
        }
        int GRbase = blockIdx.x * 128 + w * 32;
#pragma unroll
        for (int rt = 0; rt < 2; ++rt) {
            int r4 = GRbase + rt * 16 + gl * 4;
            float4 kv = *(const float4*)&kw[r4];
#pragma unroll
            for (int ct = 0; ct < 4; ++ct) {
                float v = acc[rt][ct][0] * kv.x + acc[rt][ct][1] * kv.y +
                          acc[rt][ct][2] * kv.z + acc[rt][ct][3] * kv.w;
                v += __shfl_xor(v, 16);
                if ((gl & 1) == 0) {
                    int q = (GRbase + rt * 16 + ((gl == 2) ? 8 : 0)) >> 3;
                    out[(size_t)q * 64 + ct * 16 + cl] = v;
                }
            }
        }
    }
}

extern "C" void kernel_launch(void* const* d_in, const int* in_sizes, int n_in,
                              void* d_out, int out_size, void* d_ws, size_t ws_size,
                              hipStream_t stream) {
    const float* vtx = (const float*)d_in[0];
    const float* vf  = (const float*)d_in[1];
    const float* qp  = (const float*)d_in[2];
    const float* W0  = (const float*)d_in[3];
    const float* b0  = (const float*)d_in[4];
    const float* W1  = (const float*)d_in[5];
    const float* b1  = (const float*)d_in[6];
    const float* W2  = (const float*)d_in[7];
    const float* b2  = (const float*)d_in[8];
    const float* W3  = (const float*)d_in[9];
    const float* b3  = (const float*)d_in[10];
    float*       out = (float*)d_out;

    char*      ws    = (char*)d_ws;
    float4*    vtx4  = (float4*)(ws + VTX4_OFF);
    int*       kidx  = (int*)(ws + KIDX_OFF);
    float*     kw    = (float*)(ws + KW_OFF);
    _Float16*  wfrag = (_Float16*)(ws + WFRAG_OFF);

    hipLaunchKernelGGL(prep_kernel, dim3(27), dim3(256), 0, stream, vtx, vtx4);
    hipLaunchKernelGGL(knn_kernel, dim3(NQ / 64 + 52), dim3(1024), 0, stream,
                       vtx4, qp, kidx, kw, W0, W1, W2, W3, wfrag);
    hipLaunchKernelGGL(mlp_kernel, dim3(NQ * 8 / 128), dim3(256), 0, stream,
                       vf, vtx4, qp, kidx, kw, wfrag, b0, b1, b2, b3, out);
}

// Round 19
// 205.455 us; speedup vs baseline: 1.3706x; 1.1666x over previous
//
#include <hip/hip_runtime.h>
#include <hip/hip_fp16.h>

#define NV    6890
#define NQ    32768
#define DF    64
#define NW    16      // waves per knn block
#define CHUNK 431     // ceil(NV/16)
#define SAMP  32      // sample vertices per wave (16*32 = 512 total)
#define NW32  14      // ceil(CHUNK/32) bitmask words per lane

typedef _Float16 v8h  __attribute__((ext_vector_type(8)));
typedef float    f32x4 __attribute__((ext_vector_type(4)));
typedef unsigned int       u32;
typedef unsigned long long u64;
typedef unsigned short     u16;

// ---- workspace layout (bytes) ----
static constexpr size_t VTX4_OFF  = 0;                               // float4[6912]
static constexpr size_t KIDX_OFF  = 110592;                          // int[NQ*8]
static constexpr size_t KW_OFF    = KIDX_OFF + (size_t)NQ * 8 * 4;   // float[NQ*8]
static constexpr size_t WFRAG_OFF = KW_OFF + (size_t)NQ * 8 * 4;     // f16[53248]

__device__ __forceinline__ u32 monof(float s) {
    u32 u = __float_as_uint(s);
    return (u & 0x80000000u) ? ~u : (u | 0x80000000u);
}

// distance-only sorted top-8 insert (ascending), ~24 VALU.
#define DINSERT(sv) do {                                               \
    bool c0 = (sv) < dbest[0], c1 = (sv) < dbest[1],                   \
         c2 = (sv) < dbest[2], c3 = (sv) < dbest[3],                   \
         c4 = (sv) < dbest[4], c5 = (sv) < dbest[5],                   \
         c6 = (sv) < dbest[6], c7 = (sv) < dbest[7];                   \
    dbest[7] = c7 ? (c6 ? dbest[6] : (sv)) : dbest[7];                 \
    dbest[6] = c6 ? (c5 ? dbest[5] : (sv)) : dbest[6];                 \
    dbest[5] = c5 ? (c4 ? dbest[4] : (sv)) : dbest[5];                 \
    dbest[4] = c4 ? (c3 ? dbest[3] : (sv)) : dbest[4];                 \
    dbest[3] = c3 ? (c2 ? dbest[2] : (sv)) : dbest[3];                 \
    dbest[2] = c2 ? (c1 ? dbest[1] : (sv)) : dbest[2];                 \
    dbest[1] = c1 ? (c0 ? dbest[0] : (sv)) : dbest[1];                 \
    dbest[0] = c0 ? (sv) : dbest[0];                                   \
} while (0)

// u64 sorted top-8 insert (ascending). Compares precomputed; uses OLD values.
#define KINSERT(nk) do {                                  \
    bool c0 = (nk) < key[0], c1 = (nk) < key[1],          \
         c2 = (nk) < key[2], c3 = (nk) < key[3],          \
         c4 = (nk) < key[4], c5 = (nk) < key[5],          \
         c6 = (nk) < key[6], c7 = (nk) < key[7];          \
    key[7] = c7 ? (c6 ? key[6] : (nk)) : key[7];          \
    key[6] = c6 ? (c5 ? key[5] : (nk)) : key[6];          \
    key[5] = c5 ? (c4 ? key[4] : (nk)) : key[5];          \
    key[4] = c4 ? (c3 ? key[3] : (nk)) : key[4];          \
    key[3] = c3 ? (c2 ? key[2] : (nk)) : key[3];          \
    key[2] = c2 ? (c1 ? key[1] : (nk)) : key[2];          \
    key[1] = c1 ? (c0 ? key[0] : (nk)) : key[1];          \
    key[0] = c0 ? (nk) : key[0];                          \
} while (0)

// prep: pack vertices {x,y,z,0.5|v|^2} only (wfrag fused into knn grid).
__global__ void prep_kernel(const float* __restrict__ vtx, float4* __restrict__ vtx4) {
    int i = blockIdx.x * 256 + threadIdx.x;
    if (i < NV) {
        float x = vtx[i * 3 + 0], y = vtx[i * 3 + 1], z = vtx[i * 3 + 2];
        vtx4[i] = make_float4(x, y, z, 0.5f * (x * x + y * y + z * z));
    }
}

__device__ __forceinline__ float vdist(const float4 v, float nqx, float nqy, float nqz) {
    float s = fmaf(nqx, v.x, v.w);
    s = fmaf(nqy, v.y, s);
    return fmaf(nqz, v.z, s);
}

// Exact two-phase KNN, bitmask scan (no LDS queue, no overflow path).
// Block = 64 queries (1/lane) x 16 waves; blocks >= 512 do the wfrag swizzle.
// Phase A: distance-only top-8 over 32-vertex sample slice -> LDS tree reduce
//   -> exact T = 8th smallest of 512-sample.
// Scan: chunk of 431, wave-uniform s_load float4s; survivors (s<=T) recorded
//   as REGISTER BITMASK bits (6 VALU/vertex, branchless, exact - T >= true d8
//   so every true top-8 vertex is marked).
// Drain: per-word divergent while: ctz -> reload vtx4[j] (L2) -> fp32 s ->
//   u64 key = (monotone(s)<<16)|idx, sorted top-8 insert. Ascending-bit order
//   = ascending index => reproduces top_k (distance,index) order exactly.
// Merge: log2 tree over 16 key lists.
__global__ __launch_bounds__(1024, 8) void knn_kernel(const float4* __restrict__ vtx4,
                                                      const float* __restrict__ qpts,
                                                      int* __restrict__ kidx,
                                                      float* __restrict__ kw,
                                                      const float* __restrict__ W0,
                                                      const float* __restrict__ W1,
                                                      const float* __restrict__ W2,
                                                      const float* __restrict__ W3,
                                                      _Float16* __restrict__ wfrag) {
    if (blockIdx.x >= NQ / 64) {
        // ---- fused weight-fragment swizzle: tile t=kt*NCT+ct, elem=
        // t*512+lane*8+jj, k=kt*32+(lane>>4)*8+jj, col=ct*16+(lane&15) ----
        int e = (blockIdx.x - NQ / 64) * 1024 + threadIdx.x;   // 0..53247
        const float* W; int base, NCT, C, KD;
        if      (e < 12288) { W = W0; base = 0;     NCT = 8; C = 128; KD = 67;  }
        else if (e < 28672) { W = W1; base = 12288; NCT = 8; C = 128; KD = 128; }
        else if (e < 45056) { W = W2; base = 28672; NCT = 8; C = 128; KD = 128; }
        else                { W = W3; base = 45056; NCT = 4; C = 64;  KD = 128; }
        int le = e - base;
        int t = le >> 9, r = le & 511;
        int lane = r >> 3, jj = r & 7;
        int kt = t / NCT, ct = t % NCT;
        int k = kt * 32 + (lane >> 4) * 8 + jj;
        int col = ct * 16 + (lane & 15);
        float v = (k < KD) ? W[k * C + col] : 0.0f;
        wfrag[e] = (_Float16)v;
        return;
    }

    __shared__ u64   kbuf[8][64][9];        // 36864 B; aliased f32[16][64][9] in phase A
    __shared__ float Tbc[64];
    float (*fbuf)[64][9] = (float (*)[64][9])kbuf;

    const int tid = threadIdx.x, w = tid >> 6, l = tid & 63;
    const int m = blockIdx.x * 64 + l;
    const float qx = qpts[m * 3 + 0], qy = qpts[m * 3 + 1], qz = qpts[m * 3 + 2];
    const float nqx = -qx, nqy = -qy, nqz = -qz;

    // ---- phase A: per-wave 32-vertex sample, distance-only top-8 ----
    float dbest[8];
#pragma unroll
    for (int i = 0; i < 8; ++i) dbest[i] = 3.0e38f;
    {
        const int s0 = w * SAMP;
#pragma unroll 4
        for (int j = s0; j < s0 + SAMP; ++j) {
            float s = vdist(vtx4[j], nqx, nqy, nqz);   // wave-uniform -> s_load
            DINSERT(s);
        }
    }
#pragma unroll
    for (int i = 0; i < 8; ++i) fbuf[w][l][i] = dbest[i];
    __syncthreads();

    // ---- T tree-reduce: read [st,2st) slots, merge, write [0,st) ----
#pragma unroll 1
    for (int st = 8; st >= 1; st >>= 1) {
        if (w < st) {
#pragma unroll
            for (int e = 0; e < 8; ++e) {
                float s = fbuf[w + st][l][e];
                if (s < dbest[7]) { DINSERT(s); }
            }
            if (st > 1) {
#pragma unroll
                for (int i = 0; i < 8; ++i) fbuf[w][l][i] = dbest[i];
            }
        }
        __syncthreads();
    }
    if (w == 0) Tbc[l] = dbest[7];
    __syncthreads();
    const float T = Tbc[l];

    // ---- scan: register bitmask, branchless (6 VALU/vertex) ----
    const int j0 = w * CHUNK;
    const int j1 = (j0 + CHUNK < NV) ? j0 + CHUNK : NV;
    u32 bm[NW32];
#pragma unroll 1
    for (int g = 0; g < NW32; ++g) {
        u32 word = 0;
        const int jb = j0 + g * 32;
#pragma unroll
        for (int b = 0; b < 32; ++b) {
            int j = jb + b;
            float4 v = vtx4[j < NV ? j : NV - 1];   // uniform addr -> s_load
            float s = vdist(v, nqx, nqy, nqz);
            bool c = (j < j1) && (s <= T);
            word |= c ? (1u << b) : 0u;
        }
        bm[g] = word;
    }

    // ---- drain: per-word divergent while, exact fp32 recompute + u64 keys ----
    u64 key[8];
#pragma unroll
    for (int i = 0; i < 8; ++i) key[i] = ~0ull;
#pragma unroll 1
    for (int g = 0; g < NW32; ++g) {
        u32 word = bm[g];
        const int jb = j0 + g * 32;
        while (word) {
            int b = __builtin_ctz(word);
            word &= word - 1;
            int j = jb + b;
            float4 v = vtx4[j];                     // divergent per-lane load (L2)
            float s = vdist(v, nqx, nqy, nqz);
            u64 nk = ((u64)monof(s) << 16) | (u64)j;
            if (nk < key[7]) { KINSERT(nk); }
        }
    }

    // ---- tree merge of 16 key lists: publish [st,2st) -> merge on [0,st) ----
#pragma unroll 1
    for (int st = 8; st >= 1; st >>= 1) {
        if (w >= st && w < 2 * st) {
#pragma unroll
            for (int i = 0; i < 8; ++i) kbuf[w - st][l][i] = key[i];
        }
        __syncthreads();
        if (w < st) {
#pragma unroll
            for (int e = 0; e < 8; ++e) {
                u64 nk = kbuf[w][l][e];
                if (nk < key[7]) { KINSERT(nk); }
            }
        }
        __syncthreads();
    }

    // ---- wave 0: weights + output ----
    if (w == 0) {
        float q2 = fmaf(qx, qx, fmaf(qy, qy, qz * qz));
        float inv[8], ssum = 0.0f;
        int idx8[8];
#pragma unroll
        for (int i = 0; i < 8; ++i) {
            u32 us = (u32)(key[i] >> 16);
            u32 uo = (us & 0x80000000u) ? (us & 0x7FFFFFFFu) : ~us;
            float s = __uint_as_float(uo);
            float dd = fmaf(2.0f, s, q2);
            float d = sqrtf(fmaxf(dd, 0.0f)) + 1e-9f;
            inv[i] = 1.0f / d; ssum += inv[i];
            idx8[i] = (int)(key[i] & 0xFFFFull);
        }
        float rs = 1.0f / ssum;
#pragma unroll
        for (int i = 0; i < 8; ++i) {
            kidx[m * 8 + i] = idx8[i];
            kw[m * 8 + i]   = inv[i] * rs;
        }
    }
}

// One MLP layer on this wave's 32 rows, in-place in buf. A-frag: row=l&15(+16*rt),
// k=(l>>4)*8+j; B-frag preswizzled with the SAME (lane,j)->k map (k-perm cancels).
template <int KSTEPS, int NCT, bool RELU>
__device__ __forceinline__ void mlp_layer(_Float16 (*buf)[136],
                                          const _Float16* __restrict__ frag,
                                          const float* __restrict__ bias,
                                          int w, int l) {
    const int cl = l & 15, gl = l >> 4;
    f32x4 acc[2][NCT];
#pragma unroll
    for (int ct = 0; ct < NCT; ++ct) {
        float bv = bias[ct * 16 + cl];
#pragma unroll
        for (int rt = 0; rt < 2; ++rt) acc[rt][ct] = (f32x4){bv, bv, bv, bv};
    }
    const _Float16* fb = frag + (size_t)l * 8;
#pragma unroll 1
    for (int ks = 0; ks < KSTEPS; ++ks) {
        v8h a0 = *(const v8h*)&buf[w * 32 + cl][ks * 32 + gl * 8];
        v8h a1 = *(const v8h*)&buf[w * 32 + 16 + cl][ks * 32 + gl * 8];
#pragma unroll
        for (int ct = 0; ct < NCT; ++ct) {
            v8h bf = *(const v8h*)(fb + (size_t)(ks * NCT + ct) * 512);
            acc[0][ct] = __builtin_amdgcn_mfma_f32_16x16x32_f16(a0, bf, acc[0][ct], 0, 0, 0);
            acc[1][ct] = __builtin_amdgcn_mfma_f32_16x16x32_f16(a1, bf, acc[1][ct], 0, 0, 0);
        }
    }
    // C/D layout (m89-verified): row=(l>>4)*4+j, col=l&15
#pragma unroll
    for (int rt = 0; rt < 2; ++rt)
#pragma unroll
        for (int ct = 0; ct < NCT; ++ct)
#pragma unroll
            for (int j = 0; j < 4; ++j) {
                float v = acc[rt][ct][j];
                if (RELU) v = fmaxf(v, 0.0f);
                buf[w * 32 + rt * 16 + gl * 4 + j][ct * 16 + cl] = (_Float16)v;
            }
}

// Block = 128 rows (16 queries x 8 NB), 4 waves, each wave owns 32 rows.
__global__ __launch_bounds__(256, 3) void mlp_kernel(
    const float* __restrict__ vf, const float4* __restrict__ vtx4,
    const float* __restrict__ qpts,
    const int* __restrict__ kidx, const float* __restrict__ kw,
    const _Float16* __restrict__ wfrag,
    const float* __restrict__ b0, const float* __restrict__ b1,
    const float* __restrict__ b2, const float* __restrict__ b3,
    float* __restrict__ out) {
    __shared__ _Float16 buf[128][136];
    const int tid = threadIdx.x, w = tid >> 6, l = tid & 63;
    {
        int h = l & 1;
        int lrow = w * 32 + (l >> 1);
        int grow = blockIdx.x * 128 + lrow;
        int q = grow >> 3;
        int idx = kidx[grow];
        const float4* src = (const float4*)(vf + (size_t)idx * DF) + h * 8;
#pragma unroll
        for (int t = 0; t < 4; ++t) {
            float4 a = src[2 * t], b = src[2 * t + 1];
            v8h pk = {(_Float16)a.x, (_Float16)a.y, (_Float16)a.z, (_Float16)a.w,
                      (_Float16)b.x, (_Float16)b.y, (_Float16)b.z, (_Float16)b.w};
            *(v8h*)&buf[lrow][h * 32 + t * 8] = pk;
        }
        v8h zz = {0, 0, 0, 0, 0, 0, 0, 0};
        if (h == 0) {
            float4 v = vtx4[idx];
            float qx = qpts[q * 3 + 0], qy = qpts[q * 3 + 1], qz = qpts[q * 3 + 2];
            v8h d = {(_Float16)(qx - v.x), (_Float16)(qy - v.y), (_Float16)(qz - v.z),
                     0, 0, 0, 0, 0};
            *(v8h*)&buf[lrow][64] = d;
            *(v8h*)&buf[lrow][88] = zz;
        } else {
            *(v8h*)&buf[lrow][72] = zz;
            *(v8h*)&buf[lrow][80] = zz;
        }
    }

    mlp_layer<3, 8, true>(buf, wfrag + 0,     b0, w, l);
    mlp_layer<4, 8, true>(buf, wfrag + 12288, b1, w, l);
    mlp_layer<4, 8, true>(buf, wfrag + 28672, b2, w, l);

    {
        const int cl = l & 15, gl = l >> 4;
        f32x4 acc[2][4];
#pragma unroll
        for (int ct = 0; ct < 4; ++ct) {
            float bv = b3[ct * 16 + cl];
#pragma unroll
            for (int rt = 0; rt < 2; ++rt) acc[rt][ct] = (f32x4){bv, bv, bv, bv};
        }
        const _Float16* fb = wfrag + 45056 + (size_t)l * 8;
#pragma unroll 1
        for (int ks = 0; ks < 4; ++ks) {
            v8h a0 = *(const v8h*)&buf[w * 32 + cl][ks * 32 + gl * 8];
            v8h a1 = *(const v8h*)&buf[w * 32 + 16 + cl][ks * 32 + gl * 8];
#pragma unroll
            for (int ct = 0; ct < 4; ++ct) {
                v8h bf = *(const v8h*)(fb + (size_t)(ks * 4 + ct) * 512);
                acc[0][ct] = __builtin_amdgcn_mfma_f32_16x16x32_f16(a0, bf, acc[0][ct], 0, 0, 0);
                acc[1][ct] = __builtin_amdgcn_mfma_f32_16x16x32_f16(a1, bf, acc[1][ct], 0, 0, 0);
            }
        }
        int GRbase = blockIdx.x * 128 + w * 32;
#pragma unroll
        for (int rt = 0; rt < 2; ++rt) {
            int r4 = GRbase + rt * 16 + gl * 4;
            float4 kv = *(const float4*)&kw[r4];
#pragma unroll
            for (int ct = 0; ct < 4; ++ct) {
                float v = acc[rt][ct][0] * kv.x + acc[rt][ct][1] * kv.y +
                          acc[rt][ct][2] * kv.z + acc[rt][ct][3] * kv.w;
                v += __shfl_xor(v, 16);
                if ((gl & 1) == 0) {
                    int q = (GRbase + rt * 16 + ((gl == 2) ? 8 : 0)) >> 3;
                    out[(size_t)q * 64 + ct * 16 + cl] = v;
                }
            }
        }
    }
}

extern "C" void kernel_launch(void* const* d_in, const int* in_sizes, int n_in,
                              void* d_out, int out_size, void* d_ws, size_t ws_size,
                              hipStream_t stream) {
    const float* vtx = (const float*)d_in[0];
    const float* vf  = (const float*)d_in[1];
    const float* qp  = (const float*)d_in[2];
    const float* W0  = (const float*)d_in[3];
    const float* b0  = (const float*)d_in[4];
    const float* W1  = (const float*)d_in[5];
    const float* b1  = (const float*)d_in[6];
    const float* W2  = (const float*)d_in[7];
    const float* b2  = (const float*)d_in[8];
    const float* W3  = (const float*)d_in[9];
    const float* b3  = (const float*)d_in[10];
    float*       out = (float*)d_out;

    char*      ws    = (char*)d_ws;
    float4*    vtx4  = (float4*)(ws + VTX4_OFF);
    int*       kidx  = (int*)(ws + KIDX_OFF);
    float*     kw    = (float*)(ws + KW_OFF);
    _Float16*  wfrag = (_Float16*)(ws + WFRAG_OFF);

    hipLaunchKernelGGL(prep_kernel, dim3(27), dim3(256), 0, stream, vtx, vtx4);
    hipLaunchKernelGGL(knn_kernel, dim3(NQ / 64 + 52), dim3(1024), 0, stream,
                       vtx4, qp, kidx, kw, W0, W1, W2, W3, wfrag);
    hipLaunchKernelGGL(mlp_kernel, dim3(NQ * 8 / 128), dim3(256), 0, stream,
                       vf, vtx4, qp, kidx, kw, wfrag, b0, b1, b2, b3, out);
}

// Round 20
// 151.995 us; speedup vs baseline: 1.8527x; 1.3517x over previous
//
#include <hip/hip_runtime.h>
#include <hip/hip_fp16.h>

#define NV    6890
#define NQ    32768
#define DF    64
#define NW    16      // waves per knn block
#define CHUNK 431     // ceil(NV/16)
#define SAMP  32      // sample vertices per wave (16*32 = 512 total)
#define CAPQ  20

typedef _Float16 v8h  __attribute__((ext_vector_type(8)));
typedef float    f32x4 __attribute__((ext_vector_type(4)));
typedef unsigned int       u32;
typedef unsigned long long u64;
typedef unsigned short     u16;

// ---- workspace layout (bytes) ----
static constexpr size_t VTX4_OFF  = 0;                               // float4[6912]
static constexpr size_t KIDX_OFF  = 110592;                          // int[NQ*8]
static constexpr size_t KW_OFF    = KIDX_OFF + (size_t)NQ * 8 * 4;   // float[NQ*8]
static constexpr size_t WFRAG_OFF = KW_OFF + (size_t)NQ * 8 * 4;     // f16[53248]

__device__ __forceinline__ u32 monof(float s) {
    u32 u = __float_as_uint(s);
    return (u & 0x80000000u) ? ~u : (u | 0x80000000u);
}

// Force an index into an SGPR so vtx4[.] compiles to s_load (wave-uniform by
// construction: the value is identical across lanes when called).
__device__ __forceinline__ int sgpr(int j) {
    return __builtin_amdgcn_readfirstlane(j);
}

// distance-only sorted top-8 insert (ascending), ~24 VALU.
#define DINSERT(sv) do {                                               \
    bool c0 = (sv) < dbest[0], c1 = (sv) < dbest[1],                   \
         c2 = (sv) < dbest[2], c3 = (sv) < dbest[3],                   \
         c4 = (sv) < dbest[4], c5 = (sv) < dbest[5],                   \
         c6 = (sv) < dbest[6], c7 = (sv) < dbest[7];                   \
    dbest[7] = c7 ? (c6 ? dbest[6] : (sv)) : dbest[7];                 \
    dbest[6] = c6 ? (c5 ? dbest[5] : (sv)) : dbest[6];                 \
    dbest[5] = c5 ? (c4 ? dbest[4] : (sv)) : dbest[5];                 \
    dbest[4] = c4 ? (c3 ? dbest[3] : (sv)) : dbest[4];                 \
    dbest[3] = c3 ? (c2 ? dbest[2] : (sv)) : dbest[3];                 \
    dbest[2] = c2 ? (c1 ? dbest[1] : (sv)) : dbest[2];                 \
    dbest[1] = c1 ? (c0 ? dbest[0] : (sv)) : dbest[1];                 \
    dbest[0] = c0 ? (sv) : dbest[0];                                   \
} while (0)

// u64 sorted top-8 insert (ascending). Compares precomputed; uses OLD values.
#define KINSERT(nk) do {                                  \
    bool c0 = (nk) < key[0], c1 = (nk) < key[1],          \
         c2 = (nk) < key[2], c3 = (nk) < key[3],          \
         c4 = (nk) < key[4], c5 = (nk) < key[5],          \
         c6 = (nk) < key[6], c7 = (nk) < key[7];          \
    key[7] = c7 ? (c6 ? key[6] : (nk)) : key[7];          \
    key[6] = c6 ? (c5 ? key[5] : (nk)) : key[6];          \
    key[5] = c5 ? (c4 ? key[4] : (nk)) : key[5];          \
    key[4] = c4 ? (c3 ? key[3] : (nk)) : key[4];          \
    key[3] = c3 ? (c2 ? key[2] : (nk)) : key[3];          \
    key[2] = c2 ? (c1 ? key[1] : (nk)) : key[2];          \
    key[1] = c1 ? (c0 ? key[0] : (nk)) : key[1];          \
    key[0] = c0 ? (nk) : key[0];                          \
} while (0)

#define TRYQ(sv, jv) do {                                                      \
    if ((sv) <= T) {                                                           \
        if (cnt < CAPQ) { qq[w][l][cnt] = (u16)(jv); ++cnt; }                  \
        else {                                                                 \
            u64 nk = ((u64)monof(sv) << 16) | (u64)(jv);                       \
            if (nk < key[7]) { KINSERT(nk); }                                  \
        }                                                                      \
    }                                                                          \
} while (0)

// prep: pack vertices {x,y,z,0.5|v|^2} only (wfrag fused into knn grid).
__global__ void prep_kernel(const float* __restrict__ vtx, float4* __restrict__ vtx4) {
    int i = blockIdx.x * 256 + threadIdx.x;
    if (i < NV) {
        float x = vtx[i * 3 + 0], y = vtx[i * 3 + 1], z = vtx[i * 3 + 2];
        vtx4[i] = make_float4(x, y, z, 0.5f * (x * x + y * y + z * z));
    }
}

__device__ __forceinline__ float vdist(const float4 v, float nqx, float nqy, float nqz) {
    float s = fmaf(nqx, v.x, v.w);
    s = fmaf(nqy, v.y, s);
    return fmaf(nqz, v.z, s);
}

// Exact two-phase KNN = R13 (148us champion) + readfirstlane-forced SGPR
// addressing on the sample/scan vertex streams (single-variable experiment:
// compiler was emitting divergent VMEM loads for tid>>6-derived indices).
// Block = 64 queries (1/lane) x 16 waves; blocks >= 512 do the wfrag swizzle.
// Phase A: distance-only top-8 over 32-vertex sample slice -> LDS tree reduce
//   -> exact T = 8th smallest of 512-sample.
// Scan: chunk of 431, unroll-4 SGPR-addressed s_load float4s, nested-branch
//   queue append (cap 20; overflow -> inline exact u64-key insert).
// Drain: batches of 4 (per-lane loads), exact u64 keys = (monotone(s)<<16)|idx
//   (reproduces top_k (distance,index) order). Merge: log2 tree over 16 lists.
__global__ __launch_bounds__(1024, 8) void knn_kernel(const float4* __restrict__ vtx4,
                                                      const float* __restrict__ qpts,
                                                      int* __restrict__ kidx,
                                                      float* __restrict__ kw,
                                                      const float* __restrict__ W0,
                                                      const float* __restrict__ W1,
                                                      const float* __restrict__ W2,
                                                      const float* __restrict__ W3,
                                                      _Float16* __restrict__ wfrag) {
    if (blockIdx.x >= NQ / 64) {
        // ---- fused weight-fragment swizzle: tile t=kt*NCT+ct, elem=
        // t*512+lane*8+jj, k=kt*32+(lane>>4)*8+jj, col=ct*16+(lane&15) ----
        int e = (blockIdx.x - NQ / 64) * 1024 + threadIdx.x;   // 0..53247
        const float* W; int base, NCT, C, KD;
        if      (e < 12288) { W = W0; base = 0;     NCT = 8; C = 128; KD = 67;  }
        else if (e < 28672) { W = W1; base = 12288; NCT = 8; C = 128; KD = 128; }
        else if (e < 45056) { W = W2; base = 28672; NCT = 8; C = 128; KD = 128; }
        else                { W = W3; base = 45056; NCT = 4; C = 64;  KD = 128; }
        int le = e - base;
        int t = le >> 9, r = le & 511;
        int lane = r >> 3, jj = r & 7;
        int kt = t / NCT, ct = t % NCT;
        int k = kt * 32 + (lane >> 4) * 8 + jj;
        int col = ct * 16 + (lane & 15);
        float v = (k < KD) ? W[k * C + col] : 0.0f;
        wfrag[e] = (_Float16)v;
        return;
    }

    __shared__ u64   kbuf[8][64][9];        // 36864 B; aliased f32[16][64][9] in phase A
    __shared__ u16   qq[NW][64][CAPQ];      // 40960 B
    __shared__ float Tbc[64];
    float (*fbuf)[64][9] = (float (*)[64][9])kbuf;

    const int tid = threadIdx.x, w = tid >> 6, l = tid & 63;
    const int m = blockIdx.x * 64 + l;
    const float qx = qpts[m * 3 + 0], qy = qpts[m * 3 + 1], qz = qpts[m * 3 + 2];
    const float nqx = -qx, nqy = -qy, nqz = -qz;

    // ---- phase A: per-wave 32-vertex sample, distance-only top-8 ----
    float dbest[8];
#pragma unroll
    for (int i = 0; i < 8; ++i) dbest[i] = 3.0e38f;
    {
        const int s0 = sgpr(w * SAMP);
#pragma unroll 4
        for (int j = 0; j < SAMP; ++j) {
            float s = vdist(vtx4[s0 + j], nqx, nqy, nqz);   // SGPR addr -> s_load
            DINSERT(s);
        }
    }
#pragma unroll
    for (int i = 0; i < 8; ++i) fbuf[w][l][i] = dbest[i];
    __syncthreads();

    // ---- T tree-reduce: read [st,2st) slots, merge, write [0,st) ----
#pragma unroll 1
    for (int st = 8; st >= 1; st >>= 1) {
        if (w < st) {
#pragma unroll
            for (int e = 0; e < 8; ++e) {
                float s = fbuf[w + st][l][e];
                if (s < dbest[7]) { DINSERT(s); }
            }
            if (st > 1) {
#pragma unroll
                for (int i = 0; i < 8; ++i) fbuf[w][l][i] = dbest[i];
            }
        }
        __syncthreads();
    }
    if (w == 0) Tbc[l] = dbest[7];
    __syncthreads();
    const float T = Tbc[l];

    // ---- scan: full chunk, unroll-4, SGPR-addressed loads ----
    u64 key[8];
#pragma unroll
    for (int i = 0; i < 8; ++i) key[i] = ~0ull;
    u32 cnt = 0;
    const int j0 = sgpr(w * CHUNK);
    const int j1 = sgpr((w * CHUNK + CHUNK < NV) ? w * CHUNK + CHUNK : NV);
    {
        int j = j0;
#pragma unroll 1
        for (; j + 4 <= j1; j += 4) {
            const int jb = sgpr(j);
            float4 v0 = vtx4[jb + 0], v1 = vtx4[jb + 1];
            float4 v2 = vtx4[jb + 2], v3 = vtx4[jb + 3];
            float s0 = vdist(v0, nqx, nqy, nqz);
            float s1 = vdist(v1, nqx, nqy, nqz);
            float s2 = vdist(v2, nqx, nqy, nqz);
            float s3 = vdist(v3, nqx, nqy, nqz);
            TRYQ(s0, jb + 0); TRYQ(s1, jb + 1); TRYQ(s2, jb + 2); TRYQ(s3, jb + 3);
        }
        for (; j < j1; ++j) {
            const int jb = sgpr(j);
            float s = vdist(vtx4[jb], nqx, nqy, nqz);
            TRYQ(s, jb);
        }
    }

    // ---- drain queue in batches of 4 (exact keys, per-lane loads) ----
#pragma unroll 1
    for (int b = 0; b < CAPQ; b += 4) {
        if (!__any(cnt > (u32)b)) break;
        u32 jj[4]; float4 vv[4];
#pragma unroll
        for (int t = 0; t < 4; ++t) {
            u32 qi = ((u32)(b + t) < cnt) ? (u32)qq[w][l][b + t] : 0u;
            jj[t] = qi; vv[t] = vtx4[qi];
        }
#pragma unroll
        for (int t = 0; t < 4; ++t) {
            float s = vdist(vv[t], nqx, nqy, nqz);
            u64 nk = ((u64)monof(s) << 16) | (u64)jj[t];
            nk = ((u32)(b + t) < cnt) ? nk : ~0ull;
            if (nk < key[7]) { KINSERT(nk); }
        }
    }

    // ---- tree merge of 16 key lists: publish [st,2st) -> merge on [0,st) ----
#pragma unroll 1
    for (int st = 8; st >= 1; st >>= 1) {
        if (w >= st && w < 2 * st) {
#pragma unroll
            for (int i = 0; i < 8; ++i) kbuf[w - st][l][i] = key[i];
        }
        __syncthreads();
        if (w < st) {
#pragma unroll
            for (int e = 0; e < 8; ++e) {
                u64 nk = kbuf[w][l][e];
                if (nk < key[7]) { KINSERT(nk); }
            }
        }
        __syncthreads();
    }

    // ---- wave 0: weights + output ----
    if (w == 0) {
        float q2 = fmaf(qx, qx, fmaf(qy, qy, qz * qz));
        float inv[8], ssum = 0.0f;
        int idx8[8];
#pragma unroll
        for (int i = 0; i < 8; ++i) {
            u32 us = (u32)(key[i] >> 16);
            u32 uo = (us & 0x80000000u) ? (us & 0x7FFFFFFFu) : ~us;
            float s = __uint_as_float(uo);
            float dd = fmaf(2.0f, s, q2);
            float d = sqrtf(fmaxf(dd, 0.0f)) + 1e-9f;
            inv[i] = 1.0f / d; ssum += inv[i];
            idx8[i] = (int)(key[i] & 0xFFFFull);
        }
        float rs = 1.0f / ssum;
#pragma unroll
        for (int i = 0; i < 8; ++i) {
            kidx[m * 8 + i] = idx8[i];
            kw[m * 8 + i]   = inv[i] * rs;
        }
    }
}

// One MLP layer on this wave's 32 rows, in-place in buf. A-frag: row=l&15(+16*rt),
// k=(l>>4)*8+j; B-frag preswizzled with the SAME (lane,j)->k map (k-perm cancels).
template <int KSTEPS, int NCT, bool RELU>
__device__ __forceinline__ void mlp_layer(_Float16 (*buf)[136],
                                          const _Float16* __restrict__ frag,
                                          const float* __restrict__ bias,
                                          int w, int l) {
    const int cl = l & 15, gl = l >> 4;
    f32x4 acc[2][NCT];
#pragma unroll
    for (int ct = 0; ct < NCT; ++ct) {
        float bv = bias[ct * 16 + cl];
#pragma unroll
        for (int rt = 0; rt < 2; ++rt) acc[rt][ct] = (f32x4){bv, bv, bv, bv};
    }
    const _Float16* fb = frag + (size_t)l * 8;
#pragma unroll 1
    for (int ks = 0; ks < KSTEPS; ++ks) {
        v8h a0 = *(const v8h*)&buf[w * 32 + cl][ks * 32 + gl * 8];
        v8h a1 = *(const v8h*)&buf[w * 32 + 16 + cl][ks * 32 + gl * 8];
#pragma unroll
        for (int ct = 0; ct < NCT; ++ct) {
            v8h bf = *(const v8h*)(fb + (size_t)(ks * NCT + ct) * 512);
            acc[0][ct] = __builtin_amdgcn_mfma_f32_16x16x32_f16(a0, bf, acc[0][ct], 0, 0, 0);
            acc[1][ct] = __builtin_amdgcn_mfma_f32_16x16x32_f16(a1, bf, acc[1][ct], 0, 0, 0);
        }
    }
    // C/D layout (m89-verified): row=(l>>4)*4+j, col=l&15
#pragma unroll
    for (int rt = 0; rt < 2; ++rt)
#pragma unroll
        for (int ct = 0; ct < NCT; ++ct)
#pragma unroll
            for (int j = 0; j < 4; ++j) {
                float v = acc[rt][ct][j];
                if (RELU) v = fmaxf(v, 0.0f);
                buf[w * 32 + rt * 16 + gl * 4 + j][ct * 16 + cl] = (_Float16)v;
            }
}

// Block = 128 rows (16 queries x 8 NB), 4 waves, each wave owns 32 rows.
__global__ __launch_bounds__(256, 3) void mlp_kernel(
    const float* __restrict__ vf, const float4* __restrict__ vtx4,
    const float* __restrict__ qpts,
    const int* __restrict__ kidx, const float* __restrict__ kw,
    const _Float16* __restrict__ wfrag,
    const float* __restrict__ b0, const float* __restrict__ b1,
    const float* __restrict__ b2, const float* __restrict__ b3,
    float* __restrict__ out) {
    __shared__ _Float16 buf[128][136];
    const int tid = threadIdx.x, w = tid >> 6, l = tid & 63;
    {
        int h = l & 1;
        int lrow = w * 32 + (l >> 1);
        int grow = blockIdx.x * 128 + lrow;
        int q = grow >> 3;
        int idx = kidx[grow];
        const float4* src = (const float4*)(vf + (size_t)idx * DF) + h * 8;
#pragma unroll
        for (int t = 0; t < 4; ++t) {
            float4 a = src[2 * t], b = src[2 * t + 1];
            v8h pk = {(_Float16)a.x, (_Float16)a.y, (_Float16)a.z, (_Float16)a.w,
                      (_Float16)b.x, (_Float16)b.y, (_Float16)b.z, (_Float16)b.w};
            *(v8h*)&buf[lrow][h * 32 + t * 8] = pk;
        }
        v8h zz = {0, 0, 0, 0, 0, 0, 0, 0};
        if (h == 0) {
            float4 v = vtx4[idx];
            float qx = qpts[q * 3 + 0], qy = qpts[q * 3 + 1], qz = qpts[q * 3 + 2];
            v8h d = {(_Float16)(qx - v.x), (_Float16)(qy - v.y), (_Float16)(qz - v.z),
                     0, 0, 0, 0, 0};
            *(v8h*)&buf[lrow][64] = d;
            *(v8h*)&buf[lrow][88] = zz;
        } else {
            *(v8h*)&buf[lrow][72] = zz;
            *(v8h*)&buf[lrow][80] = zz;
        }
    }

    mlp_layer<3, 8, true>(buf, wfrag + 0,     b0, w, l);
    mlp_layer<4, 8, true>(buf, wfrag + 12288, b1, w, l);
    mlp_layer<4, 8, true>(buf, wfrag + 28672, b2, w, l);

    {
        const int cl = l & 15, gl = l >> 4;
        f32x4 acc[2][4];
#pragma unroll
        for (int ct = 0; ct < 4; ++ct) {
            float bv = b3[ct * 16 + cl];
#pragma unroll
            for (int rt = 0; rt < 2; ++rt) acc[rt][ct] = (f32x4){bv, bv, bv, bv};
        }
        const _Float16* fb = wfrag + 45056 + (size_t)l * 8;
#pragma unroll 1
        for (int ks = 0; ks < 4; ++ks) {
            v8h a0 = *(const v8h*)&buf[w * 32 + cl][ks * 32 + gl * 8];
            v8h a1 = *(const v8h*)&buf[w * 32 + 16 + cl][ks * 32 + gl * 8];
#pragma unroll
            for (int ct = 0; ct < 4; ++ct) {
                v8h bf = *(const v8h*)(fb + (size_t)(ks * 4 + ct) * 512);
                acc[0][ct] = __builtin_amdgcn_mfma_f32_16x16x32_f16(a0, bf, acc[0][ct], 0, 0, 0);
                acc[1][ct] = __builtin_amdgcn_mfma_f32_16x16x32_f16(a1, bf, acc[1][ct], 0, 0, 0);
            }
        }
        int GRbase = blockIdx.x * 128 + w * 32;
#pragma unroll
        for (int rt = 0; rt < 2; ++rt) {
            int r4 = GRbase + rt * 16 + gl * 4;
            float4 kv = *(const float4*)&kw[r4];
#pragma unroll
            for (int ct = 0; ct < 4; ++ct) {
                float v = acc[rt][ct][0] * kv.x + acc[rt][ct][1] * kv.y +
                          acc[rt][ct][2] * kv.z + acc[rt][ct][3] * kv.w;
                v += __shfl_xor(v, 16);
                if ((gl & 1) == 0) {
                    int q = (GRbase + rt * 16 + ((gl == 2) ? 8 : 0)) >> 3;
                    out[(size_t)q * 64 + ct * 16 + cl] = v;
                }
            }
        }
    }
}

extern "C" void kernel_launch(void* const* d_in, const int* in_sizes, int n_in,
                              void* d_out, int out_size, void* d_ws, size_t ws_size,
                              hipStream_t stream) {
    const float* vtx = (const float*)d_in[0];
    const float* vf  = (const float*)d_in[1];
    const float* qp  = (const float*)d_in[2];
    const float* W0  = (const float*)d_in[3];
    const float* b0  = (const float*)d_in[4];
    const float* W1  = (const float*)d_in[5];
    const float* b1  = (const float*)d_in[6];
    const float* W2  = (const float*)d_in[7];
    const float* b2  = (const float*)d_in[8];
    const float* W3  = (const float*)d_in[9];
    const float* b3  = (const float*)d_in[10];
    float*       out = (float*)d_out;

    char*      ws    = (char*)d_ws;
    float4*    vtx4  = (float4*)(ws + VTX4_OFF);
    int*       kidx  = (int*)(ws + KIDX_OFF);
    float*     kw    = (float*)(ws + KW_OFF);
    _Float16*  wfrag = (_Float16*)(ws + WFRAG_OFF);

    hipLaunchKernelGGL(prep_kernel, dim3(27), dim3(256), 0, stream, vtx, vtx4);
    hipLaunchKernelGGL(knn_kernel, dim3(NQ / 64 + 52), dim3(1024), 0, stream,
                       vtx4, qp, kidx, kw, W0, W1, W2, W3, wfrag);
    hipLaunchKernelGGL(mlp_kernel, dim3(NQ * 8 / 128), dim3(256), 0, stream,
                       vf, vtx4, qp, kidx, kw, wfrag, b0, b1, b2, b3, out);
}